// Round 4
// baseline (462.702 us; speedup 1.0000x reference)
//
#include <hip/hip_runtime.h>

#define SEG 24
#define DD  32
#define HEPS 1e-7f
#define N_ITERS 10

__device__ __forceinline__ float frcp(float x) { return __builtin_amdgcn_rcpf(x); }

// coef = arccosh(a)/sqrt(a^2-1), caller guarantees a >= 1+1e-7
__device__ __forceinline__ float acosh_coef(float a) {
    float am = fmaf(a, a, -1.0f);
    float s  = sqrtf(am);
    return __logf(a + s) * frcp(s);
}

__global__ __launch_bounds__(256, 4)
void slmw_kernel(const float* __restrict__ x0, const float* __restrict__ x1,
                 const float* __restrict__ x2, const float* __restrict__ x3,
                 const float* __restrict__ W0, const float* __restrict__ b0,
                 const float* __restrict__ W1, const float* __restrict__ b1,
                 const float* __restrict__ W2, const float* __restrict__ b2,
                 const float* __restrict__ W3, const float* __restrict__ b3,
                 const float* __restrict__ es, const float* __restrict__ lw,
                 float* __restrict__ out, int n_items)
{
    const int item = blockIdx.x * blockDim.x + threadIdx.x;
    if (item >= n_items) return;

    const float ts = tanhf(es[0]);

    float l0 = lw[0], l1 = lw[1], l2 = lw[2], l3 = lw[3];
    float mx = fmaxf(fmaxf(l0, l1), fmaxf(l2, l3));
    float e0 = __expf(l0 - mx), e1 = __expf(l1 - mx),
          e2 = __expf(l2 - mx), e3 = __expf(l3 - mx);
    float inv = frcp(e0 + e1 + e2 + e3);
    float w4[4] = { e0 * inv, e1 * inv, e2 * inv, e3 * inv };

    const float* xs[4] = { x0, x1, x2, x3 };
    const float* Ws[4] = { W0, W1, W2, W3 };
    const float* bs[4] = { b0, b1, b2, b3 };

    const size_t base = (size_t)item * SEG;
    const size_t osz  = (size_t)n_items * DD;

    float tau[4];   // time components of h_s

    // ================= encode + to_hyperbolic; h_s streamed to out =========
    #pragma unroll
    for (int s = 0; s < 4; ++s) {
        const float4* sp = reinterpret_cast<const float4*>(xs[s] + base);
        float seg[SEG];
        #pragma unroll
        for (int j = 0; j < SEG / 4; ++j) {
            float4 v = sp[j];
            seg[4*j+0] = v.x; seg[4*j+1] = v.y; seg[4*j+2] = v.z; seg[4*j+3] = v.w;
        }

        float u[DD];
        #pragma unroll
        for (int d = 0; d < DD; ++d) {
            float z = bs[s][d];                           // wave-uniform s_load
            #pragma unroll
            for (int k = 0; k < SEG; ++k)
                z = fmaf(seg[k], Ws[s][d * SEG + k], z);
            u[d] = z * ts;
        }

        // safe_expmap0: <u,u>_L = sum(u^2) - 2*u0^2, 4-way partials
        float q[4] = {0.f, 0.f, 0.f, 0.f};
        #pragma unroll
        for (int d = 0; d < DD; ++d) q[d & 3] = fmaf(u[d], u[d], q[d & 3]);
        float sq = (q[0] + q[1]) + (q[2] + q[3]) - 2.0f * u[0] * u[0];
        sq = fmaxf(sq, 1e-12f);
        float nrm = sqrtf(sq);
        float ep = __expf(nrm), em = frcp(ep);
        float sh = 0.5f * (ep - em);
        float sc = sh * frcp(fmaxf(nrm, HEPS));

        float y[DD];
        float r[4] = {0.f, 0.f, 0.f, 0.f};
        #pragma unroll
        for (int d = 1; d < DD; ++d) {
            float yv = sc * u[d];
            y[d] = yv;
            r[d & 3] = fmaf(yv, yv, r[d & 3]);
        }
        y[0] = sqrtf(1.0f + (r[0] + r[1]) + (r[2] + r[3]));   // projx time comp
        tau[s] = y[0];

        float* op = out + (size_t)s * osz + (size_t)item * DD;
        #pragma unroll
        for (int j = 0; j < DD / 4; ++j) {
            float4 v = { y[4*j+0], y[4*j+1], y[4*j+2], y[4*j+3] };
            reinterpret_cast<float4*>(op)[j] = v;
        }
    }

    // ================= Gram matrix of {h_0..h_3, o} under <,>_L =============
    const float4* p0 = reinterpret_cast<const float4*>(out + 0 * osz + (size_t)item * DD);
    const float4* p1 = reinterpret_cast<const float4*>(out + 1 * osz + (size_t)item * DD);
    const float4* p2 = reinterpret_cast<const float4*>(out + 2 * osz + (size_t)item * DD);
    const float4* p3 = reinterpret_cast<const float4*>(out + 3 * osz + (size_t)item * DD);

    float d00=0.f,d01=0.f,d02=0.f,d03=0.f,d11=0.f,d12=0.f,d13=0.f,d22=0.f,d23=0.f,d33=0.f;
    #pragma unroll
    for (int c = 0; c < DD / 4; ++c) {
        float4 a0 = p0[c], a1 = p1[c], a2 = p2[c], a3 = p3[c];
        d00 = fmaf(a0.x,a0.x, fmaf(a0.y,a0.y, fmaf(a0.z,a0.z, fmaf(a0.w,a0.w, d00))));
        d01 = fmaf(a0.x,a1.x, fmaf(a0.y,a1.y, fmaf(a0.z,a1.z, fmaf(a0.w,a1.w, d01))));
        d02 = fmaf(a0.x,a2.x, fmaf(a0.y,a2.y, fmaf(a0.z,a2.z, fmaf(a0.w,a2.w, d02))));
        d03 = fmaf(a0.x,a3.x, fmaf(a0.y,a3.y, fmaf(a0.z,a3.z, fmaf(a0.w,a3.w, d03))));
        d11 = fmaf(a1.x,a1.x, fmaf(a1.y,a1.y, fmaf(a1.z,a1.z, fmaf(a1.w,a1.w, d11))));
        d12 = fmaf(a1.x,a2.x, fmaf(a1.y,a2.y, fmaf(a1.z,a2.z, fmaf(a1.w,a2.w, d12))));
        d13 = fmaf(a1.x,a3.x, fmaf(a1.y,a3.y, fmaf(a1.z,a3.z, fmaf(a1.w,a3.w, d13))));
        d22 = fmaf(a2.x,a2.x, fmaf(a2.y,a2.y, fmaf(a2.z,a2.z, fmaf(a2.w,a2.w, d22))));
        d23 = fmaf(a2.x,a3.x, fmaf(a2.y,a3.y, fmaf(a2.z,a3.z, fmaf(a2.w,a3.w, d23))));
        d33 = fmaf(a3.x,a3.x, fmaf(a3.y,a3.y, fmaf(a3.z,a3.z, fmaf(a3.w,a3.w, d33))));
    }

    float G[5][5];
    G[0][0] = fmaf(-2.0f*tau[0], tau[0], d00);
    G[0][1] = G[1][0] = fmaf(-2.0f*tau[0], tau[1], d01);
    G[0][2] = G[2][0] = fmaf(-2.0f*tau[0], tau[2], d02);
    G[0][3] = G[3][0] = fmaf(-2.0f*tau[0], tau[3], d03);
    G[1][1] = fmaf(-2.0f*tau[1], tau[1], d11);
    G[1][2] = G[2][1] = fmaf(-2.0f*tau[1], tau[2], d12);
    G[1][3] = G[3][1] = fmaf(-2.0f*tau[1], tau[3], d13);
    G[2][2] = fmaf(-2.0f*tau[2], tau[2], d22);
    G[2][3] = G[3][2] = fmaf(-2.0f*tau[2], tau[3], d23);
    G[3][3] = fmaf(-2.0f*tau[3], tau[3], d33);
    G[0][4] = G[4][0] = -tau[0];
    G[1][4] = G[4][1] = -tau[1];
    G[2][4] = G[4][2] = -tau[2];
    G[3][4] = G[4][3] = -tau[3];
    G[4][4] = -1.0f;

    // ================= fusion init in 5-d coordinates =======================
    float beta[5], g[5];
    {
        float bo = 0.0f;
        #pragma unroll
        for (int s = 0; s < 4; ++s) {
            float alpha = fmaxf(tau[s], 1.0f + HEPS);
            float c = w4[s] * acosh_coef(alpha);
            beta[s] = c;
            bo = fmaf(-c, alpha, bo);
        }
        beta[4] = bo;

        float gq = 0.0f;
        #pragma unroll
        for (int i = 0; i < 5; ++i) {
            float gi = 0.0f;
            #pragma unroll
            for (int j = 0; j < 5; ++j) gi = fmaf(G[i][j], beta[j], gi);
            gq = fmaf(gi, beta[i], gq);
        }
        float sq = fmaxf(gq, 1e-12f);
        float nrm = sqrtf(sq);
        float ep = __expf(nrm), em = frcp(ep);
        float ch = 0.5f * (ep + em);
        float sh = 0.5f * (ep - em);
        float sc = sh * frcp(fmaxf(nrm, HEPS));
        #pragma unroll
        for (int s = 0; s < 4; ++s) beta[s] *= sc;
        beta[4] = fmaf(sc, beta[4], ch);        // expmap0 = ch*o + sc*t0

        float xx = 0.0f;
        #pragma unroll
        for (int i = 0; i < 5; ++i) {
            float gi = 0.0f;
            #pragma unroll
            for (int j = 0; j < 5; ++j) gi = fmaf(G[i][j], beta[j], gi);
            g[i] = gi;
            xx = fmaf(gi, beta[i], xx);
        }
        float xt = fmaf(beta[0], tau[0], fmaf(beta[1], tau[1],
                   fmaf(beta[2], tau[2], fmaf(beta[3], tau[3], beta[4]))));
        float tc = sqrtf(fmaf(xt, xt, 1.0f + xx));
        float dl = tc - xt;
        beta[4] += dl;
        #pragma unroll
        for (int i = 0; i < 5; ++i) g[i] = fmaf(dl, G[i][4], g[i]);
    }

    // ================= Frechet refinement, 10 iters in 5-d ==================
    for (int it = 0; it < N_ITERS; ++it) {
        float c[4], S = 0.0f;
        #pragma unroll
        for (int s = 0; s < 4; ++s) {
            float alpha = fmaxf(-g[s], 1.0f + HEPS);
            c[s] = w4[s] * acosh_coef(alpha);
            S = fmaf(c[s], alpha, S);
        }
        float gam[5];
        #pragma unroll
        for (int s = 0; s < 4; ++s) gam[s] = fmaf(-S, beta[s], c[s]);
        gam[4] = -S * beta[4];

        float Gg[5], qq = 0.0f;
        #pragma unroll
        for (int i = 0; i < 5; ++i) {
            float gi = 0.0f;
            #pragma unroll
            for (int j = 0; j < 5; ++j) gi = fmaf(G[i][j], gam[j], gi);
            Gg[i] = gi;
            qq = fmaf(gi, gam[i], qq);
        }
        float sq = fmaxf(0.25f * qq, 1e-12f);
        float nrm = sqrtf(sq);
        float ep = __expf(nrm), em = frcp(ep);
        float ch = 0.5f * (ep + em);
        float sh = 0.5f * (ep - em);
        float sc = 0.5f * sh * frcp(fmaxf(nrm, HEPS));

        float xx = 0.0f;
        #pragma unroll
        for (int i = 0; i < 5; ++i) {
            beta[i] = fmaf(ch, beta[i], sc * gam[i]);
            g[i]    = fmaf(ch, g[i],    sc * Gg[i]);   // g = G*beta by linearity
            xx = fmaf(g[i], beta[i], xx);
        }
        float xt = fmaf(beta[0], tau[0], fmaf(beta[1], tau[1],
                   fmaf(beta[2], tau[2], fmaf(beta[3], tau[3], beta[4]))));
        float tc = sqrtf(fmaf(xt, xt, 1.0f + xx));
        float dl = tc - xt;
        beta[4] += dl;
        #pragma unroll
        for (int i = 0; i < 5; ++i) g[i] = fmaf(dl, G[i][4], g[i]);
    }

    // ================= reconstruction: combined = sum beta_s h_s + beta_4 o =
    float4* po = reinterpret_cast<float4*>(out + (size_t)4 * osz + (size_t)item * DD);
    #pragma unroll
    for (int cidx = 0; cidx < DD / 4; ++cidx) {
        float4 a0 = p0[cidx], a1 = p1[cidx], a2 = p2[cidx], a3 = p3[cidx];
        float4 r;
        r.x = fmaf(beta[0],a0.x, fmaf(beta[1],a1.x, fmaf(beta[2],a2.x, beta[3]*a3.x)));
        r.y = fmaf(beta[0],a0.y, fmaf(beta[1],a1.y, fmaf(beta[2],a2.y, beta[3]*a3.y)));
        r.z = fmaf(beta[0],a0.z, fmaf(beta[1],a1.z, fmaf(beta[2],a2.z, beta[3]*a3.z)));
        r.w = fmaf(beta[0],a0.w, fmaf(beta[1],a1.w, fmaf(beta[2],a2.w, beta[3]*a3.w)));
        if (cidx == 0) r.x += beta[4];
        po[cidx] = r;
    }
}

extern "C" void kernel_launch(void* const* d_in, const int* in_sizes, int n_in,
                              void* d_out, int out_size, void* d_ws, size_t ws_size,
                              hipStream_t stream)
{
    const float* x0 = (const float*)d_in[0];
    const float* x1 = (const float*)d_in[1];
    const float* x2 = (const float*)d_in[2];
    const float* x3 = (const float*)d_in[3];
    const float* W0 = (const float*)d_in[4];
    const float* b0 = (const float*)d_in[5];
    const float* W1 = (const float*)d_in[6];
    const float* b1 = (const float*)d_in[7];
    const float* W2 = (const float*)d_in[8];
    const float* b2 = (const float*)d_in[9];
    const float* W3 = (const float*)d_in[10];
    const float* b3 = (const float*)d_in[11];
    const float* es = (const float*)d_in[12];
    const float* lw = (const float*)d_in[13];

    const int n_items = in_sizes[0] / SEG;   // 262144
    const int block = 256;
    const int grid  = (n_items + block - 1) / block;

    slmw_kernel<<<grid, block, 0, stream>>>(x0, x1, x2, x3,
                                            W0, b0, W1, b1, W2, b2, W3, b3,
                                            es, lw, (float*)d_out, n_items);
}

// Round 5
// 181.121 us; speedup vs baseline: 2.5547x; 2.5547x over previous
//
#include <hip/hip_runtime.h>

#define SEG 24
#define DD  32
#define HEPS 1e-7f
#define N_ITERS 10

__device__ __forceinline__ float frcp(float x) { return __builtin_amdgcn_rcpf(x); }

// coef = arccosh(a)/sqrt(a^2-1), caller guarantees a >= 1+1e-7
__device__ __forceinline__ float acosh_coef(float a) {
    float am = fmaf(a, a, -1.0f);
    float s  = sqrtf(am);
    return __logf(a + s) * frcp(s);
}

// ============ K1: encode + safe_expmap0 + projx, one (item,stream)/thread ===
__global__ __launch_bounds__(256)
void encode_kernel(const float* __restrict__ x0, const float* __restrict__ x1,
                   const float* __restrict__ x2, const float* __restrict__ x3,
                   const float* __restrict__ W0, const float* __restrict__ b0,
                   const float* __restrict__ W1, const float* __restrict__ b1,
                   const float* __restrict__ W2, const float* __restrict__ b2,
                   const float* __restrict__ W3, const float* __restrict__ b3,
                   const float* __restrict__ es,
                   float* __restrict__ out, int n_items)
{
    const int item = blockIdx.x * blockDim.x + threadIdx.x;
    if (item >= n_items) return;
    const int s = blockIdx.y;           // wave-uniform stream id

    const float* xp; const float* Wp; const float* bp;
    if      (s == 0) { xp = x0; Wp = W0; bp = b0; }
    else if (s == 1) { xp = x1; Wp = W1; bp = b1; }
    else if (s == 2) { xp = x2; Wp = W2; bp = b2; }
    else             { xp = x3; Wp = W3; bp = b3; }

    const float ts = tanhf(es[0]);

    float seg[SEG];
    const float4* sp = reinterpret_cast<const float4*>(xp + (size_t)item * SEG);
    #pragma unroll
    for (int j = 0; j < SEG / 4; ++j) {
        float4 v = sp[j];
        seg[4*j+0] = v.x; seg[4*j+1] = v.y; seg[4*j+2] = v.z; seg[4*j+3] = v.w;
    }

    float u[DD];
    #pragma unroll
    for (int d = 0; d < DD; ++d) {
        float z = bp[d];                         // wave-uniform -> scalar load
        #pragma unroll
        for (int k = 0; k < SEG; ++k)
            z = fmaf(seg[k], Wp[d * SEG + k], z);
        u[d] = z * ts;
    }

    // <u,u>_L = sum(u^2) - 2*u0^2, 4-way partials
    float q0 = 0.f, q1 = 0.f, q2 = 0.f, q3 = 0.f;
    #pragma unroll
    for (int d = 0; d < DD; d += 4) {
        q0 = fmaf(u[d+0], u[d+0], q0);
        q1 = fmaf(u[d+1], u[d+1], q1);
        q2 = fmaf(u[d+2], u[d+2], q2);
        q3 = fmaf(u[d+3], u[d+3], q3);
    }
    float sq = (q0 + q1) + (q2 + q3) - 2.0f * u[0] * u[0];
    sq = fmaxf(sq, 1e-12f);
    float nrm = sqrtf(sq);
    float ep = __expf(nrm), em = frcp(ep);
    float sh = 0.5f * (ep - em);
    float sc = sh * frcp(fmaxf(nrm, HEPS));

    float y[DD];
    float r0 = 0.f, r1 = 0.f, r2 = 0.f, r3 = 0.f;
    #pragma unroll
    for (int d = 1; d < DD; ++d) {
        float yv = sc * u[d];
        y[d] = yv;
        if ((d & 3) == 0) r0 = fmaf(yv, yv, r0);
        else if ((d & 3) == 1) r1 = fmaf(yv, yv, r1);
        else if ((d & 3) == 2) r2 = fmaf(yv, yv, r2);
        else r3 = fmaf(yv, yv, r3);
    }
    y[0] = sqrtf(1.0f + (r0 + r1) + (r2 + r3));   // projx time component

    float* op = out + (size_t)s * ((size_t)n_items * DD) + (size_t)item * DD;
    #pragma unroll
    for (int j = 0; j < DD / 4; ++j) {
        float4 v = { y[4*j+0], y[4*j+1], y[4*j+2], y[4*j+3] };
        reinterpret_cast<float4*>(op)[j] = v;
    }
}

// ============ K2: Gram + 5-d Frechet + reconstruction, one item/thread ======
// Matvec with the symmetric 5x5 Gram (last row/col = -tau_i, G44 = -1)
#define GMV(o0,o1,o2,o3,o4, v0,v1,v2,v3,v4)                                   \
    o0 = fmaf(G00,(v0), fmaf(G01,(v1), fmaf(G02,(v2), fmaf(G03,(v3), nt0*(v4))))); \
    o1 = fmaf(G01,(v0), fmaf(G11,(v1), fmaf(G12,(v2), fmaf(G13,(v3), nt1*(v4))))); \
    o2 = fmaf(G02,(v0), fmaf(G12,(v1), fmaf(G22,(v2), fmaf(G23,(v3), nt2*(v4))))); \
    o3 = fmaf(G03,(v0), fmaf(G13,(v1), fmaf(G23,(v2), fmaf(G33,(v3), nt3*(v4))))); \
    o4 = fmaf(nt0,(v0), fmaf(nt1,(v1), fmaf(nt2,(v2), fmaf(nt3,(v3), -(v4)))));

#define DOT5(a0,a1,a2,a3,a4, c0,c1,c2,c3,c4) \
    fmaf((a0),(c0), fmaf((a1),(c1), fmaf((a2),(c2), fmaf((a3),(c3), (a4)*(c4)))))

__global__ __launch_bounds__(256)
void fusion_kernel(const float* __restrict__ lw,
                   float* __restrict__ out, int n_items)
{
    const int item = blockIdx.x * blockDim.x + threadIdx.x;
    if (item >= n_items) return;

    float l0 = lw[0], l1 = lw[1], l2 = lw[2], l3 = lw[3];
    float mxw = fmaxf(fmaxf(l0, l1), fmaxf(l2, l3));
    float e0 = __expf(l0 - mxw), e1 = __expf(l1 - mxw),
          e2 = __expf(l2 - mxw), e3 = __expf(l3 - mxw);
    float winv = frcp(e0 + e1 + e2 + e3);
    float w0 = e0 * winv, w1 = e1 * winv, w2 = e2 * winv, w3 = e3 * winv;

    const size_t osz = (size_t)n_items * DD;
    const float4* p0 = reinterpret_cast<const float4*>(out + 0 * osz + (size_t)item * DD);
    const float4* p1 = reinterpret_cast<const float4*>(out + 1 * osz + (size_t)item * DD);
    const float4* p2 = reinterpret_cast<const float4*>(out + 2 * osz + (size_t)item * DD);
    const float4* p3 = reinterpret_cast<const float4*>(out + 3 * osz + (size_t)item * DD);

    // ---- Gram: 10 Euclidean dots + time components ----
    float d00=0.f,d01=0.f,d02=0.f,d03=0.f,d11=0.f,
          d12=0.f,d13=0.f,d22=0.f,d23=0.f,d33=0.f;
    float tau0=0.f, tau1=0.f, tau2=0.f, tau3=0.f;
    #pragma unroll
    for (int c = 0; c < DD / 4; ++c) {
        float4 a0 = p0[c], a1 = p1[c], a2 = p2[c], a3 = p3[c];
        if (c == 0) { tau0 = a0.x; tau1 = a1.x; tau2 = a2.x; tau3 = a3.x; }
        d00 = fmaf(a0.x,a0.x, fmaf(a0.y,a0.y, fmaf(a0.z,a0.z, fmaf(a0.w,a0.w, d00))));
        d01 = fmaf(a0.x,a1.x, fmaf(a0.y,a1.y, fmaf(a0.z,a1.z, fmaf(a0.w,a1.w, d01))));
        d02 = fmaf(a0.x,a2.x, fmaf(a0.y,a2.y, fmaf(a0.z,a2.z, fmaf(a0.w,a2.w, d02))));
        d03 = fmaf(a0.x,a3.x, fmaf(a0.y,a3.y, fmaf(a0.z,a3.z, fmaf(a0.w,a3.w, d03))));
        d11 = fmaf(a1.x,a1.x, fmaf(a1.y,a1.y, fmaf(a1.z,a1.z, fmaf(a1.w,a1.w, d11))));
        d12 = fmaf(a1.x,a2.x, fmaf(a1.y,a2.y, fmaf(a1.z,a2.z, fmaf(a1.w,a2.w, d12))));
        d13 = fmaf(a1.x,a3.x, fmaf(a1.y,a3.y, fmaf(a1.z,a3.z, fmaf(a1.w,a3.w, d13))));
        d22 = fmaf(a2.x,a2.x, fmaf(a2.y,a2.y, fmaf(a2.z,a2.z, fmaf(a2.w,a2.w, d22))));
        d23 = fmaf(a2.x,a3.x, fmaf(a2.y,a3.y, fmaf(a2.z,a3.z, fmaf(a2.w,a3.w, d23))));
        d33 = fmaf(a3.x,a3.x, fmaf(a3.y,a3.y, fmaf(a3.z,a3.z, fmaf(a3.w,a3.w, d33))));
    }

    // Minkowski corrections: G_st = d_st - 2*tau_s*tau_t ; border = -tau
    float G00 = fmaf(-2.0f*tau0, tau0, d00);
    float G01 = fmaf(-2.0f*tau0, tau1, d01);
    float G02 = fmaf(-2.0f*tau0, tau2, d02);
    float G03 = fmaf(-2.0f*tau0, tau3, d03);
    float G11 = fmaf(-2.0f*tau1, tau1, d11);
    float G12 = fmaf(-2.0f*tau1, tau2, d12);
    float G13 = fmaf(-2.0f*tau1, tau3, d13);
    float G22 = fmaf(-2.0f*tau2, tau2, d22);
    float G23 = fmaf(-2.0f*tau2, tau3, d23);
    float G33 = fmaf(-2.0f*tau3, tau3, d33);
    float nt0 = -tau0, nt1 = -tau1, nt2 = -tau2, nt3 = -tau3;

    // ---- fusion init in 5-d coordinates ----
    float b0v, b1v, b2v, b3v, b4v, g0, g1, g2, g3, g4;
    {
        float al0 = fmaxf(tau0, 1.0f + HEPS);
        float al1 = fmaxf(tau1, 1.0f + HEPS);
        float al2 = fmaxf(tau2, 1.0f + HEPS);
        float al3 = fmaxf(tau3, 1.0f + HEPS);
        float cc0 = w0 * acosh_coef(al0);
        float cc1 = w1 * acosh_coef(al1);
        float cc2 = w2 * acosh_coef(al2);
        float cc3 = w3 * acosh_coef(al3);
        b0v = cc0; b1v = cc1; b2v = cc2; b3v = cc3;
        b4v = -DOT5(cc0, cc1, cc2, cc3, 0.0f, al0, al1, al2, al3, 0.0f);

        GMV(g0, g1, g2, g3, g4, b0v, b1v, b2v, b3v, b4v);
        float gq = DOT5(g0, g1, g2, g3, g4, b0v, b1v, b2v, b3v, b4v);
        float sq = fmaxf(gq, 1e-12f);
        float nrm = sqrtf(sq);
        float ep = __expf(nrm), em = frcp(ep);
        float ch = 0.5f * (ep + em);
        float sc = 0.5f * (ep - em) * frcp(fmaxf(nrm, HEPS));
        b0v *= sc; b1v *= sc; b2v *= sc; b3v *= sc;
        b4v = fmaf(sc, b4v, ch);                 // expmap0 = ch*o + sc*t0

        GMV(g0, g1, g2, g3, g4, b0v, b1v, b2v, b3v, b4v);
        float xx = DOT5(g0, g1, g2, g3, g4, b0v, b1v, b2v, b3v, b4v);
        float xt = DOT5(b0v, b1v, b2v, b3v, b4v, tau0, tau1, tau2, tau3, 1.0f);
        float tc = sqrtf(fmaf(xt, xt, 1.0f + xx));
        float dl = tc - xt;
        b4v += dl;
        g0 = fmaf(dl, nt0, g0); g1 = fmaf(dl, nt1, g1);
        g2 = fmaf(dl, nt2, g2); g3 = fmaf(dl, nt3, g3);
        g4 -= dl;
    }

    // ---- Frechet refinement, 10 iters in 5-d (invariant: g = G*beta) ----
    for (int it = 0; it < N_ITERS; ++it) {
        float al0 = fmaxf(-g0, 1.0f + HEPS);
        float al1 = fmaxf(-g1, 1.0f + HEPS);
        float al2 = fmaxf(-g2, 1.0f + HEPS);
        float al3 = fmaxf(-g3, 1.0f + HEPS);
        float cc0 = w0 * acosh_coef(al0);
        float cc1 = w1 * acosh_coef(al1);
        float cc2 = w2 * acosh_coef(al2);
        float cc3 = w3 * acosh_coef(al3);
        float S = DOT5(cc0, cc1, cc2, cc3, 0.0f, al0, al1, al2, al3, 0.0f);

        float gm0 = fmaf(-S, b0v, cc0);
        float gm1 = fmaf(-S, b1v, cc1);
        float gm2 = fmaf(-S, b2v, cc2);
        float gm3 = fmaf(-S, b3v, cc3);
        float gm4 = -S * b4v;

        float Gg0, Gg1, Gg2, Gg3, Gg4;
        GMV(Gg0, Gg1, Gg2, Gg3, Gg4, gm0, gm1, gm2, gm3, gm4);
        float qq = DOT5(Gg0, Gg1, Gg2, Gg3, Gg4, gm0, gm1, gm2, gm3, gm4);

        float sq = fmaxf(0.25f * qq, 1e-12f);
        float nrm = sqrtf(sq);
        float ep = __expf(nrm), em = frcp(ep);
        float ch = 0.5f * (ep + em);
        float sc = 0.25f * (ep - em) * frcp(fmaxf(nrm, HEPS)); // 0.5*sinh * 0.5

        b0v = fmaf(ch, b0v, sc * gm0);
        b1v = fmaf(ch, b1v, sc * gm1);
        b2v = fmaf(ch, b2v, sc * gm2);
        b3v = fmaf(ch, b3v, sc * gm3);
        b4v = fmaf(ch, b4v, sc * gm4);
        g0  = fmaf(ch, g0, sc * Gg0);
        g1  = fmaf(ch, g1, sc * Gg1);
        g2  = fmaf(ch, g2, sc * Gg2);
        g3  = fmaf(ch, g3, sc * Gg3);
        g4  = fmaf(ch, g4, sc * Gg4);

        float xx = DOT5(g0, g1, g2, g3, g4, b0v, b1v, b2v, b3v, b4v);
        float xt = DOT5(b0v, b1v, b2v, b3v, b4v, tau0, tau1, tau2, tau3, 1.0f);
        float tc = sqrtf(fmaf(xt, xt, 1.0f + xx));
        float dl = tc - xt;
        b4v += dl;
        g0 = fmaf(dl, nt0, g0); g1 = fmaf(dl, nt1, g1);
        g2 = fmaf(dl, nt2, g2); g3 = fmaf(dl, nt3, g3);
        g4 -= dl;
    }

    // ---- reconstruction: combined = sum beta_s*h_s + beta_4*o ----
    float4* po = reinterpret_cast<float4*>(out + (size_t)4 * osz + (size_t)item * DD);
    #pragma unroll
    for (int c = 0; c < DD / 4; ++c) {
        float4 a0 = p0[c], a1 = p1[c], a2 = p2[c], a3 = p3[c];
        float4 r;
        r.x = fmaf(b0v,a0.x, fmaf(b1v,a1.x, fmaf(b2v,a2.x, b3v*a3.x)));
        r.y = fmaf(b0v,a0.y, fmaf(b1v,a1.y, fmaf(b2v,a2.y, b3v*a3.y)));
        r.z = fmaf(b0v,a0.z, fmaf(b1v,a1.z, fmaf(b2v,a2.z, b3v*a3.z)));
        r.w = fmaf(b0v,a0.w, fmaf(b1v,a1.w, fmaf(b2v,a2.w, b3v*a3.w)));
        if (c == 0) r.x += b4v;
        po[c] = r;
    }
}

extern "C" void kernel_launch(void* const* d_in, const int* in_sizes, int n_in,
                              void* d_out, int out_size, void* d_ws, size_t ws_size,
                              hipStream_t stream)
{
    const float* x0 = (const float*)d_in[0];
    const float* x1 = (const float*)d_in[1];
    const float* x2 = (const float*)d_in[2];
    const float* x3 = (const float*)d_in[3];
    const float* W0 = (const float*)d_in[4];
    const float* b0 = (const float*)d_in[5];
    const float* W1 = (const float*)d_in[6];
    const float* b1 = (const float*)d_in[7];
    const float* W2 = (const float*)d_in[8];
    const float* b2 = (const float*)d_in[9];
    const float* W3 = (const float*)d_in[10];
    const float* b3 = (const float*)d_in[11];
    const float* es = (const float*)d_in[12];
    const float* lw = (const float*)d_in[13];

    const int n_items = in_sizes[0] / SEG;   // 262144
    const int block = 256;
    const int gx = (n_items + block - 1) / block;

    dim3 grid1(gx, 4, 1);
    encode_kernel<<<grid1, block, 0, stream>>>(x0, x1, x2, x3,
                                               W0, b0, W1, b1, W2, b2, W3, b3,
                                               es, (float*)d_out, n_items);

    fusion_kernel<<<gx, block, 0, stream>>>(lw, (float*)d_out, n_items);
}

// Round 6
// 155.178 us; speedup vs baseline: 2.9817x; 1.1672x over previous
//
#include <hip/hip_runtime.h>

#define SEG 24
#define DD  32
#define HEPS 1e-7f
#define N_ITERS 10

__device__ __forceinline__ float frcp(float x) { return __builtin_amdgcn_rcpf(x); }

// quad_perm [1,0,3,2] -> xor1 ; [2,3,0,1] -> xor2 ; pure-VALU cross-lane
__device__ __forceinline__ float qx1(float x) {
    return __int_as_float(__builtin_amdgcn_mov_dpp(__float_as_int(x), 0xB1, 0xF, 0xF, true));
}
__device__ __forceinline__ float qx2(float x) {
    return __int_as_float(__builtin_amdgcn_mov_dpp(__float_as_int(x), 0x4E, 0xF, 0xF, true));
}
__device__ __forceinline__ float qsum(float x) {   // sum over the 4 lanes of a quad
    x += qx1(x);
    x += qx2(x);
    return x;
}

// coef = arccosh(a)/sqrt(a^2-1), caller guarantees a >= 1+1e-7
__device__ __forceinline__ float acosh_coef(float a) {
    float am = fmaf(a, a, -1.0f);
    float s  = sqrtf(am);
    return __logf(a + s) * frcp(s);
}

// 8-dim partial dot + quad reduce -> full 32-dim Euclidean dot on all 4 lanes
__device__ __forceinline__ float edot8(const float a[8], const float b[8]) {
    float x = fmaf(a[0], b[0], a[1] * b[1]);
    float y = fmaf(a[2], b[2], a[3] * b[3]);
    float z = fmaf(a[4], b[4], a[5] * b[5]);
    float w = fmaf(a[6], b[6], a[7] * b[7]);
    return qsum((x + y) + (z + w));
}

// ============ K1: encode + safe_expmap0 + projx, one (item,stream)/thread ===
__global__ __launch_bounds__(256)
void encode_kernel(const float* __restrict__ x0, const float* __restrict__ x1,
                   const float* __restrict__ x2, const float* __restrict__ x3,
                   const float* __restrict__ W0, const float* __restrict__ b0,
                   const float* __restrict__ W1, const float* __restrict__ b1,
                   const float* __restrict__ W2, const float* __restrict__ b2,
                   const float* __restrict__ W3, const float* __restrict__ b3,
                   const float* __restrict__ es,
                   float* __restrict__ out, int n_items)
{
    const int item = blockIdx.x * blockDim.x + threadIdx.x;
    if (item >= n_items) return;
    const int s = blockIdx.y;           // wave-uniform stream id

    const float* xp; const float* Wp; const float* bp;
    if      (s == 0) { xp = x0; Wp = W0; bp = b0; }
    else if (s == 1) { xp = x1; Wp = W1; bp = b1; }
    else if (s == 2) { xp = x2; Wp = W2; bp = b2; }
    else             { xp = x3; Wp = W3; bp = b3; }

    const float ts = tanhf(es[0]);

    float seg[SEG];
    const float4* sp = reinterpret_cast<const float4*>(xp + (size_t)item * SEG);
    #pragma unroll
    for (int j = 0; j < SEG / 4; ++j) {
        float4 v = sp[j];
        seg[4*j+0] = v.x; seg[4*j+1] = v.y; seg[4*j+2] = v.z; seg[4*j+3] = v.w;
    }

    float u[DD];
    #pragma unroll
    for (int d = 0; d < DD; ++d) {
        float z = bp[d];                         // wave-uniform -> scalar load
        #pragma unroll
        for (int k = 0; k < SEG; ++k)
            z = fmaf(seg[k], Wp[d * SEG + k], z);
        u[d] = z * ts;
    }

    // <u,u>_L = sum(u^2) - 2*u0^2, 4-way partials
    float q0 = 0.f, q1 = 0.f, q2 = 0.f, q3 = 0.f;
    #pragma unroll
    for (int d = 0; d < DD; d += 4) {
        q0 = fmaf(u[d+0], u[d+0], q0);
        q1 = fmaf(u[d+1], u[d+1], q1);
        q2 = fmaf(u[d+2], u[d+2], q2);
        q3 = fmaf(u[d+3], u[d+3], q3);
    }
    float sq = (q0 + q1) + (q2 + q3) - 2.0f * u[0] * u[0];
    sq = fmaxf(sq, 1e-12f);
    float nrm = sqrtf(sq);
    float ep = __expf(nrm), em = frcp(ep);
    float sh = 0.5f * (ep - em);
    float sc = sh * frcp(fmaxf(nrm, HEPS));

    // scale space part in place, accumulate its squared norm
    float r0 = 0.f, r1 = 0.f, r2 = 0.f, r3 = 0.f;
    #pragma unroll
    for (int d = 1; d < DD; ++d) {
        float yv = sc * u[d];
        u[d] = yv;
        if ((d & 3) == 0) r0 = fmaf(yv, yv, r0);
        else if ((d & 3) == 1) r1 = fmaf(yv, yv, r1);
        else if ((d & 3) == 2) r2 = fmaf(yv, yv, r2);
        else r3 = fmaf(yv, yv, r3);
    }
    u[0] = sqrtf(1.0f + (r0 + r1) + (r2 + r3));   // projx time component

    float* op = out + (size_t)s * ((size_t)n_items * DD) + (size_t)item * DD;
    #pragma unroll
    for (int j = 0; j < DD / 4; ++j) {
        float4 v = { u[4*j+0], u[4*j+1], u[4*j+2], u[4*j+3] };
        reinterpret_cast<float4*>(op)[j] = v;
    }
}

// ============ K2: fusion, 4 lanes per item; h in registers, single read =====
// Matvec with the symmetric 5x5 Gram (last row/col = -tau_i, G44 = -1)
#define GMV(o0,o1,o2,o3,o4, v0,v1,v2,v3,v4)                                   \
    o0 = fmaf(G00,(v0), fmaf(G01,(v1), fmaf(G02,(v2), fmaf(G03,(v3), nt0*(v4))))); \
    o1 = fmaf(G01,(v0), fmaf(G11,(v1), fmaf(G12,(v2), fmaf(G13,(v3), nt1*(v4))))); \
    o2 = fmaf(G02,(v0), fmaf(G12,(v1), fmaf(G22,(v2), fmaf(G23,(v3), nt2*(v4))))); \
    o3 = fmaf(G03,(v0), fmaf(G13,(v1), fmaf(G23,(v2), fmaf(G33,(v3), nt3*(v4))))); \
    o4 = fmaf(nt0,(v0), fmaf(nt1,(v1), fmaf(nt2,(v2), fmaf(nt3,(v3), -(v4)))));

#define DOT5(a0,a1,a2,a3,a4, c0,c1,c2,c3,c4) \
    fmaf((a0),(c0), fmaf((a1),(c1), fmaf((a2),(c2), fmaf((a3),(c3), (a4)*(c4)))))

__global__ __launch_bounds__(256)
void fusion_kernel(const float* __restrict__ lw,
                   float* __restrict__ out, int n_items)
{
    const int T    = blockIdx.x * blockDim.x + threadIdx.x;
    const int item = T >> 2;
    const int sub  = T & 3;
    if (item >= n_items) return;

    float l0 = lw[0], l1 = lw[1], l2 = lw[2], l3 = lw[3];
    float mxw = fmaxf(fmaxf(l0, l1), fmaxf(l2, l3));
    float e0 = __expf(l0 - mxw), e1 = __expf(l1 - mxw),
          e2 = __expf(l2 - mxw), e3 = __expf(l3 - mxw);
    float winv = frcp(e0 + e1 + e2 + e3);
    float w0 = e0 * winv, w1 = e1 * winv, w2 = e2 * winv, w3 = e3 * winv;

    const size_t osz = (size_t)n_items * DD;

    // ---- single coalesced read: lane sub owns dims [8*sub, 8*sub+8) ----
    float hv[4][8];
    #pragma unroll
    for (int s = 0; s < 4; ++s) {
        const float4* p = reinterpret_cast<const float4*>(
            out + (size_t)s * osz + (size_t)item * DD + sub * 8);
        float4 a = p[0], b = p[1];
        hv[s][0] = a.x; hv[s][1] = a.y; hv[s][2] = a.z; hv[s][3] = a.w;
        hv[s][4] = b.x; hv[s][5] = b.y; hv[s][6] = b.z; hv[s][7] = b.w;
    }

    // time components, broadcast to whole quad
    const float is0 = (sub == 0) ? 1.0f : 0.0f;
    float tau0 = qsum(is0 * hv[0][0]);
    float tau1 = qsum(is0 * hv[1][0]);
    float tau2 = qsum(is0 * hv[2][0]);
    float tau3 = qsum(is0 * hv[3][0]);

    // ---- Gram: 10 Euclidean dots via quad reduce ----
    float d00 = edot8(hv[0], hv[0]);
    float d01 = edot8(hv[0], hv[1]);
    float d02 = edot8(hv[0], hv[2]);
    float d03 = edot8(hv[0], hv[3]);
    float d11 = edot8(hv[1], hv[1]);
    float d12 = edot8(hv[1], hv[2]);
    float d13 = edot8(hv[1], hv[3]);
    float d22 = edot8(hv[2], hv[2]);
    float d23 = edot8(hv[2], hv[3]);
    float d33 = edot8(hv[3], hv[3]);

    // Minkowski corrections: G_st = d_st - 2*tau_s*tau_t ; border = -tau
    float G00 = fmaf(-2.0f*tau0, tau0, d00);
    float G01 = fmaf(-2.0f*tau0, tau1, d01);
    float G02 = fmaf(-2.0f*tau0, tau2, d02);
    float G03 = fmaf(-2.0f*tau0, tau3, d03);
    float G11 = fmaf(-2.0f*tau1, tau1, d11);
    float G12 = fmaf(-2.0f*tau1, tau2, d12);
    float G13 = fmaf(-2.0f*tau1, tau3, d13);
    float G22 = fmaf(-2.0f*tau2, tau2, d22);
    float G23 = fmaf(-2.0f*tau2, tau3, d23);
    float G33 = fmaf(-2.0f*tau3, tau3, d33);
    float nt0 = -tau0, nt1 = -tau1, nt2 = -tau2, nt3 = -tau3;

    // ---- fusion init in 5-d coordinates (replicated per lane) ----
    float b0v, b1v, b2v, b3v, b4v, g0, g1, g2, g3, g4;
    {
        float al0 = fmaxf(tau0, 1.0f + HEPS);
        float al1 = fmaxf(tau1, 1.0f + HEPS);
        float al2 = fmaxf(tau2, 1.0f + HEPS);
        float al3 = fmaxf(tau3, 1.0f + HEPS);
        float cc0 = w0 * acosh_coef(al0);
        float cc1 = w1 * acosh_coef(al1);
        float cc2 = w2 * acosh_coef(al2);
        float cc3 = w3 * acosh_coef(al3);
        b0v = cc0; b1v = cc1; b2v = cc2; b3v = cc3;
        b4v = -DOT5(cc0, cc1, cc2, cc3, 0.0f, al0, al1, al2, al3, 0.0f);

        GMV(g0, g1, g2, g3, g4, b0v, b1v, b2v, b3v, b4v);
        float gq = DOT5(g0, g1, g2, g3, g4, b0v, b1v, b2v, b3v, b4v);
        float sq = fmaxf(gq, 1e-12f);
        float nrm = sqrtf(sq);
        float ep = __expf(nrm), em = frcp(ep);
        float ch = 0.5f * (ep + em);
        float sc = 0.5f * (ep - em) * frcp(fmaxf(nrm, HEPS));
        b0v *= sc; b1v *= sc; b2v *= sc; b3v *= sc;
        b4v = fmaf(sc, b4v, ch);                 // expmap0 = ch*o + sc*t0

        GMV(g0, g1, g2, g3, g4, b0v, b1v, b2v, b3v, b4v);
        float xx = DOT5(g0, g1, g2, g3, g4, b0v, b1v, b2v, b3v, b4v);
        float xt = DOT5(b0v, b1v, b2v, b3v, b4v, tau0, tau1, tau2, tau3, 1.0f);
        float tc = sqrtf(fmaf(xt, xt, 1.0f + xx));
        float dl = tc - xt;
        b4v += dl;
        g0 = fmaf(dl, nt0, g0); g1 = fmaf(dl, nt1, g1);
        g2 = fmaf(dl, nt2, g2); g3 = fmaf(dl, nt3, g3);
        g4 -= dl;
    }

    // ---- Frechet refinement, 10 iters in 5-d (invariant: g = G*beta) ----
    for (int it = 0; it < N_ITERS; ++it) {
        float al0 = fmaxf(-g0, 1.0f + HEPS);
        float al1 = fmaxf(-g1, 1.0f + HEPS);
        float al2 = fmaxf(-g2, 1.0f + HEPS);
        float al3 = fmaxf(-g3, 1.0f + HEPS);
        float cc0 = w0 * acosh_coef(al0);
        float cc1 = w1 * acosh_coef(al1);
        float cc2 = w2 * acosh_coef(al2);
        float cc3 = w3 * acosh_coef(al3);
        float S = DOT5(cc0, cc1, cc2, cc3, 0.0f, al0, al1, al2, al3, 0.0f);

        float gm0 = fmaf(-S, b0v, cc0);
        float gm1 = fmaf(-S, b1v, cc1);
        float gm2 = fmaf(-S, b2v, cc2);
        float gm3 = fmaf(-S, b3v, cc3);
        float gm4 = -S * b4v;

        float Gg0, Gg1, Gg2, Gg3, Gg4;
        GMV(Gg0, Gg1, Gg2, Gg3, Gg4, gm0, gm1, gm2, gm3, gm4);
        float qq = DOT5(Gg0, Gg1, Gg2, Gg3, Gg4, gm0, gm1, gm2, gm3, gm4);

        float sq = fmaxf(0.25f * qq, 1e-12f);
        float nrm = sqrtf(sq);
        float ep = __expf(nrm), em = frcp(ep);
        float ch = 0.5f * (ep + em);
        float sc = 0.25f * (ep - em) * frcp(fmaxf(nrm, HEPS)); // 0.5*sinh * 0.5

        b0v = fmaf(ch, b0v, sc * gm0);
        b1v = fmaf(ch, b1v, sc * gm1);
        b2v = fmaf(ch, b2v, sc * gm2);
        b3v = fmaf(ch, b3v, sc * gm3);
        b4v = fmaf(ch, b4v, sc * gm4);
        g0  = fmaf(ch, g0, sc * Gg0);
        g1  = fmaf(ch, g1, sc * Gg1);
        g2  = fmaf(ch, g2, sc * Gg2);
        g3  = fmaf(ch, g3, sc * Gg3);
        g4  = fmaf(ch, g4, sc * Gg4);

        float xx = DOT5(g0, g1, g2, g3, g4, b0v, b1v, b2v, b3v, b4v);
        float xt = DOT5(b0v, b1v, b2v, b3v, b4v, tau0, tau1, tau2, tau3, 1.0f);
        float tc = sqrtf(fmaf(xt, xt, 1.0f + xx));
        float dl = tc - xt;
        b4v += dl;
        g0 = fmaf(dl, nt0, g0); g1 = fmaf(dl, nt1, g1);
        g2 = fmaf(dl, nt2, g2); g3 = fmaf(dl, nt3, g3);
        g4 -= dl;
    }

    // ---- reconstruction from registers: combined = sum beta_s*h_s + b4*o ----
    float r[8];
    #pragma unroll
    for (int j = 0; j < 8; ++j)
        r[j] = fmaf(b0v, hv[0][j], fmaf(b1v, hv[1][j],
               fmaf(b2v, hv[2][j], b3v * hv[3][j])));
    if (sub == 0) r[0] += b4v;

    float4* po = reinterpret_cast<float4*>(
        out + (size_t)4 * osz + (size_t)item * DD + sub * 8);
    po[0] = make_float4(r[0], r[1], r[2], r[3]);
    po[1] = make_float4(r[4], r[5], r[6], r[7]);
}

extern "C" void kernel_launch(void* const* d_in, const int* in_sizes, int n_in,
                              void* d_out, int out_size, void* d_ws, size_t ws_size,
                              hipStream_t stream)
{
    const float* x0 = (const float*)d_in[0];
    const float* x1 = (const float*)d_in[1];
    const float* x2 = (const float*)d_in[2];
    const float* x3 = (const float*)d_in[3];
    const float* W0 = (const float*)d_in[4];
    const float* b0 = (const float*)d_in[5];
    const float* W1 = (const float*)d_in[6];
    const float* b1 = (const float*)d_in[7];
    const float* W2 = (const float*)d_in[8];
    const float* b2 = (const float*)d_in[9];
    const float* W3 = (const float*)d_in[10];
    const float* b3 = (const float*)d_in[11];
    const float* es = (const float*)d_in[12];
    const float* lw = (const float*)d_in[13];

    const int n_items = in_sizes[0] / SEG;   // 262144
    const int block = 256;
    const int gx = (n_items + block - 1) / block;

    dim3 grid1(gx, 4, 1);
    encode_kernel<<<grid1, block, 0, stream>>>(x0, x1, x2, x3,
                                               W0, b0, W1, b1, W2, b2, W3, b3,
                                               es, (float*)d_out, n_items);

    const int n_threads = n_items * 4;
    const int gx2 = (n_threads + block - 1) / block;
    fusion_kernel<<<gx2, block, 0, stream>>>(lw, (float*)d_out, n_items);
}

// Round 8
// 154.357 us; speedup vs baseline: 2.9976x; 1.0053x over previous
//
#include <hip/hip_runtime.h>

#define SEG 24
#define DD  32
#define HEPS 1e-7f
#define N_ITERS 10

typedef _Float16 h2 __attribute__((ext_vector_type(2)));
typedef __fp16   f16v2 __attribute__((ext_vector_type(2)));

__device__ __forceinline__ float frcp(float x) { return __builtin_amdgcn_rcpf(x); }

__device__ __forceinline__ float qx1(float x) {
    return __int_as_float(__builtin_amdgcn_mov_dpp(__float_as_int(x), 0xB1, 0xF, 0xF, true));
}
__device__ __forceinline__ float qx2(float x) {
    return __int_as_float(__builtin_amdgcn_mov_dpp(__float_as_int(x), 0x4E, 0xF, 0xF, true));
}
__device__ __forceinline__ float qsum(float x) {
    x += qx1(x);
    x += qx2(x);
    return x;
}

__device__ __forceinline__ float acosh_coef(float a) {
    float am = fmaf(a, a, -1.0f);
    float s  = sqrtf(am);
    return __logf(a + s) * frcp(s);
}

__device__ __forceinline__ float edot8(const float a[8], const float b[8]) {
    float x = fmaf(a[0], b[0], a[1] * b[1]);
    float y = fmaf(a[2], b[2], a[3] * b[3]);
    float z = fmaf(a[4], b[4], a[5] * b[5]);
    float w = fmaf(a[6], b[6], a[7] * b[7]);
    return qsum((x + y) + (z + w));
}

// pack two f32 -> one dword of f16x2 (round-toward-zero pack instr)
__device__ __forceinline__ unsigned pk_u32(float a, float b) {
    union { f16v2 f; unsigned u; } c;
    c.f = __builtin_amdgcn_cvt_pkrtz(a, b);
    return c.u;
}
__device__ __forceinline__ h2 pk_h2(float a, float b) {
    union { f16v2 f; h2 h; } c;
    c.f = __builtin_amdgcn_cvt_pkrtz(a, b);
    return c.h;
}
__device__ __forceinline__ h2 as_h2(unsigned u) {
    union { unsigned u; h2 h; } c; c.u = u; return c.h;
}

// ws layout (dwords): [0,1536) packed W f16x2 (s*384 + r*12 + j)
//                     [1536,1664) b f32 (s*32 + d) ; [1664] tanh(es)
#define WS_B_OFF 1536
#define WS_TS_OFF 1664

// ============ K0: pack W to f16x2, copy b, tanh(es) -> d_ws =================
__global__ __launch_bounds__(256)
void prep_kernel(const float* __restrict__ W0, const float* __restrict__ b0,
                 const float* __restrict__ W1, const float* __restrict__ b1,
                 const float* __restrict__ W2, const float* __restrict__ b2,
                 const float* __restrict__ W3, const float* __restrict__ b3,
                 const float* __restrict__ es, unsigned* __restrict__ ws)
{
    const int t = blockIdx.x * blockDim.x + threadIdx.x;
    const float* Ws[4] = { W0, W1, W2, W3 };
    const float* bs[4] = { b0, b1, b2, b3 };
    if (t < 1536) {
        int s = t / 384, rem = t % 384, r = rem / 12, j = rem % 12;
        float a = Ws[s][r * SEG + 2 * j];
        float b = Ws[s][r * SEG + 2 * j + 1];
        ws[t] = pk_u32(a, b);
    } else if (t < 1664) {
        int p = t - 1536;
        reinterpret_cast<float*>(ws)[WS_B_OFF + p] = bs[p / 32][p % 32];
    } else if (t == 1664) {
        reinterpret_cast<float*>(ws)[WS_TS_OFF] = tanhf(es[0]);
    }
}

// ============ K1: encode via fdot2 + safe_expmap0 + projx ===================
__global__ __launch_bounds__(256)
void encode_kernel(const float* __restrict__ x0, const float* __restrict__ x1,
                   const float* __restrict__ x2, const float* __restrict__ x3,
                   const unsigned* __restrict__ ws,
                   float* __restrict__ out, int n_items)
{
    const int item = blockIdx.x * blockDim.x + threadIdx.x;
    if (item >= n_items) return;
    const int s = blockIdx.y;           // wave-uniform stream id

    const float* xp;
    if      (s == 0) xp = x0;
    else if (s == 1) xp = x1;
    else if (s == 2) xp = x2;
    else             xp = x3;

    const unsigned* W2p = ws + (size_t)s * 384;                 // s_load source
    const float*    B2p = reinterpret_cast<const float*>(ws) + WS_B_OFF + s * 32;
    const float     ts  = reinterpret_cast<const float*>(ws)[WS_TS_OFF];

    // load segment (f32) and pack to f16x2
    float seg[SEG];
    const float4* sp = reinterpret_cast<const float4*>(xp + (size_t)item * SEG);
    #pragma unroll
    for (int j = 0; j < SEG / 4; ++j) {
        float4 v = sp[j];
        seg[4*j+0] = v.x; seg[4*j+1] = v.y; seg[4*j+2] = v.z; seg[4*j+3] = v.w;
    }
    h2 sp2[SEG / 2];
    #pragma unroll
    for (int j = 0; j < SEG / 2; ++j)
        sp2[j] = pk_h2(seg[2*j], seg[2*j+1]);

    float u[DD];
    #pragma unroll
    for (int d = 0; d < DD; ++d) {
        float z = B2p[d];                          // wave-uniform -> s_load
        #pragma unroll
        for (int j = 0; j < SEG / 2; ++j)
            z = __builtin_amdgcn_fdot2(sp2[j], as_h2(W2p[d * 12 + j]), z, false);
        u[d] = z * ts;
    }

    // <u,u>_L = sum(u^2) - 2*u0^2, 4-way partials
    float q0 = 0.f, q1 = 0.f, q2 = 0.f, q3 = 0.f;
    #pragma unroll
    for (int d = 0; d < DD; d += 4) {
        q0 = fmaf(u[d+0], u[d+0], q0);
        q1 = fmaf(u[d+1], u[d+1], q1);
        q2 = fmaf(u[d+2], u[d+2], q2);
        q3 = fmaf(u[d+3], u[d+3], q3);
    }
    float sq = (q0 + q1) + (q2 + q3) - 2.0f * u[0] * u[0];
    sq = fmaxf(sq, 1e-12f);
    float nrm = sqrtf(sq);
    float ep = __expf(nrm), em = frcp(ep);
    float sh = 0.5f * (ep - em);
    float sc = sh * frcp(fmaxf(nrm, HEPS));

    float r0 = 0.f, r1 = 0.f, r2 = 0.f, r3 = 0.f;
    #pragma unroll
    for (int d = 1; d < DD; ++d) {
        float yv = sc * u[d];
        u[d] = yv;
        if ((d & 3) == 0) r0 = fmaf(yv, yv, r0);
        else if ((d & 3) == 1) r1 = fmaf(yv, yv, r1);
        else if ((d & 3) == 2) r2 = fmaf(yv, yv, r2);
        else r3 = fmaf(yv, yv, r3);
    }
    u[0] = sqrtf(1.0f + (r0 + r1) + (r2 + r3));   // projx time component

    float* op = out + (size_t)s * ((size_t)n_items * DD) + (size_t)item * DD;
    #pragma unroll
    for (int j = 0; j < DD / 4; ++j) {
        float4 v = { u[4*j+0], u[4*j+1], u[4*j+2], u[4*j+3] };
        reinterpret_cast<float4*>(op)[j] = v;
    }
}

// ============ K2: fusion, 4 lanes per item; h in registers, single read =====
#define GMV(o0,o1,o2,o3,o4, v0,v1,v2,v3,v4)                                   \
    o0 = fmaf(G00,(v0), fmaf(G01,(v1), fmaf(G02,(v2), fmaf(G03,(v3), nt0*(v4))))); \
    o1 = fmaf(G01,(v0), fmaf(G11,(v1), fmaf(G12,(v2), fmaf(G13,(v3), nt1*(v4))))); \
    o2 = fmaf(G02,(v0), fmaf(G12,(v1), fmaf(G22,(v2), fmaf(G23,(v3), nt2*(v4))))); \
    o3 = fmaf(G03,(v0), fmaf(G13,(v1), fmaf(G23,(v2), fmaf(G33,(v3), nt3*(v4))))); \
    o4 = fmaf(nt0,(v0), fmaf(nt1,(v1), fmaf(nt2,(v2), fmaf(nt3,(v3), -(v4)))));

#define DOT5(a0,a1,a2,a3,a4, c0,c1,c2,c3,c4) \
    fmaf((a0),(c0), fmaf((a1),(c1), fmaf((a2),(c2), fmaf((a3),(c3), (a4)*(c4)))))

__global__ __launch_bounds__(256)
void fusion_kernel(const float* __restrict__ lw,
                   float* __restrict__ out, int n_items)
{
    const int T    = blockIdx.x * blockDim.x + threadIdx.x;
    const int item = T >> 2;
    const int sub  = T & 3;
    if (item >= n_items) return;

    float l0 = lw[0], l1 = lw[1], l2 = lw[2], l3 = lw[3];
    float mxw = fmaxf(fmaxf(l0, l1), fmaxf(l2, l3));
    float e0 = __expf(l0 - mxw), e1 = __expf(l1 - mxw),
          e2 = __expf(l2 - mxw), e3 = __expf(l3 - mxw);
    float winv = frcp(e0 + e1 + e2 + e3);
    float w0 = e0 * winv, w1 = e1 * winv, w2 = e2 * winv, w3 = e3 * winv;

    const size_t osz = (size_t)n_items * DD;

    float hv[4][8];
    #pragma unroll
    for (int s = 0; s < 4; ++s) {
        const float4* p = reinterpret_cast<const float4*>(
            out + (size_t)s * osz + (size_t)item * DD + sub * 8);
        float4 a = p[0], b = p[1];
        hv[s][0] = a.x; hv[s][1] = a.y; hv[s][2] = a.z; hv[s][3] = a.w;
        hv[s][4] = b.x; hv[s][5] = b.y; hv[s][6] = b.z; hv[s][7] = b.w;
    }

    const float is0 = (sub == 0) ? 1.0f : 0.0f;
    float tau0 = qsum(is0 * hv[0][0]);
    float tau1 = qsum(is0 * hv[1][0]);
    float tau2 = qsum(is0 * hv[2][0]);
    float tau3 = qsum(is0 * hv[3][0]);

    float d00 = edot8(hv[0], hv[0]);
    float d01 = edot8(hv[0], hv[1]);
    float d02 = edot8(hv[0], hv[2]);
    float d03 = edot8(hv[0], hv[3]);
    float d11 = edot8(hv[1], hv[1]);
    float d12 = edot8(hv[1], hv[2]);
    float d13 = edot8(hv[1], hv[3]);
    float d22 = edot8(hv[2], hv[2]);
    float d23 = edot8(hv[2], hv[3]);
    float d33 = edot8(hv[3], hv[3]);

    float G00 = fmaf(-2.0f*tau0, tau0, d00);
    float G01 = fmaf(-2.0f*tau0, tau1, d01);
    float G02 = fmaf(-2.0f*tau0, tau2, d02);
    float G03 = fmaf(-2.0f*tau0, tau3, d03);
    float G11 = fmaf(-2.0f*tau1, tau1, d11);
    float G12 = fmaf(-2.0f*tau1, tau2, d12);
    float G13 = fmaf(-2.0f*tau1, tau3, d13);
    float G22 = fmaf(-2.0f*tau2, tau2, d22);
    float G23 = fmaf(-2.0f*tau2, tau3, d23);
    float G33 = fmaf(-2.0f*tau3, tau3, d33);
    float nt0 = -tau0, nt1 = -tau1, nt2 = -tau2, nt3 = -tau3;

    float b0v, b1v, b2v, b3v, b4v, g0, g1, g2, g3, g4;
    {
        float al0 = fmaxf(tau0, 1.0f + HEPS);
        float al1 = fmaxf(tau1, 1.0f + HEPS);
        float al2 = fmaxf(tau2, 1.0f + HEPS);
        float al3 = fmaxf(tau3, 1.0f + HEPS);
        float cc0 = w0 * acosh_coef(al0);
        float cc1 = w1 * acosh_coef(al1);
        float cc2 = w2 * acosh_coef(al2);
        float cc3 = w3 * acosh_coef(al3);
        b0v = cc0; b1v = cc1; b2v = cc2; b3v = cc3;
        b4v = -DOT5(cc0, cc1, cc2, cc3, 0.0f, al0, al1, al2, al3, 0.0f);

        GMV(g0, g1, g2, g3, g4, b0v, b1v, b2v, b3v, b4v);
        float gq = DOT5(g0, g1, g2, g3, g4, b0v, b1v, b2v, b3v, b4v);
        float sq = fmaxf(gq, 1e-12f);
        float nrm = sqrtf(sq);
        float ep = __expf(nrm), em = frcp(ep);
        float ch = 0.5f * (ep + em);
        float sc = 0.5f * (ep - em) * frcp(fmaxf(nrm, HEPS));
        b0v *= sc; b1v *= sc; b2v *= sc; b3v *= sc;
        b4v = fmaf(sc, b4v, ch);

        GMV(g0, g1, g2, g3, g4, b0v, b1v, b2v, b3v, b4v);
        float xx = DOT5(g0, g1, g2, g3, g4, b0v, b1v, b2v, b3v, b4v);
        float xt = DOT5(b0v, b1v, b2v, b3v, b4v, tau0, tau1, tau2, tau3, 1.0f);
        float tc = sqrtf(fmaf(xt, xt, 1.0f + xx));
        float dl = tc - xt;
        b4v += dl;
        g0 = fmaf(dl, nt0, g0); g1 = fmaf(dl, nt1, g1);
        g2 = fmaf(dl, nt2, g2); g3 = fmaf(dl, nt3, g3);
        g4 -= dl;
    }

    for (int it = 0; it < N_ITERS; ++it) {
        float al0 = fmaxf(-g0, 1.0f + HEPS);
        float al1 = fmaxf(-g1, 1.0f + HEPS);
        float al2 = fmaxf(-g2, 1.0f + HEPS);
        float al3 = fmaxf(-g3, 1.0f + HEPS);
        float cc0 = w0 * acosh_coef(al0);
        float cc1 = w1 * acosh_coef(al1);
        float cc2 = w2 * acosh_coef(al2);
        float cc3 = w3 * acosh_coef(al3);
        float S = DOT5(cc0, cc1, cc2, cc3, 0.0f, al0, al1, al2, al3, 0.0f);

        float gm0 = fmaf(-S, b0v, cc0);
        float gm1 = fmaf(-S, b1v, cc1);
        float gm2 = fmaf(-S, b2v, cc2);
        float gm3 = fmaf(-S, b3v, cc3);
        float gm4 = -S * b4v;

        float Gg0, Gg1, Gg2, Gg3, Gg4;
        GMV(Gg0, Gg1, Gg2, Gg3, Gg4, gm0, gm1, gm2, gm3, gm4);
        float qq = DOT5(Gg0, Gg1, Gg2, Gg3, Gg4, gm0, gm1, gm2, gm3, gm4);

        float sq = fmaxf(0.25f * qq, 1e-12f);
        float nrm = sqrtf(sq);
        float ep = __expf(nrm), em = frcp(ep);
        float ch = 0.5f * (ep + em);
        float sc = 0.25f * (ep - em) * frcp(fmaxf(nrm, HEPS));

        b0v = fmaf(ch, b0v, sc * gm0);
        b1v = fmaf(ch, b1v, sc * gm1);
        b2v = fmaf(ch, b2v, sc * gm2);
        b3v = fmaf(ch, b3v, sc * gm3);
        b4v = fmaf(ch, b4v, sc * gm4);
        g0  = fmaf(ch, g0, sc * Gg0);
        g1  = fmaf(ch, g1, sc * Gg1);
        g2  = fmaf(ch, g2, sc * Gg2);
        g3  = fmaf(ch, g3, sc * Gg3);
        g4  = fmaf(ch, g4, sc * Gg4);

        float xx = DOT5(g0, g1, g2, g3, g4, b0v, b1v, b2v, b3v, b4v);
        float xt = DOT5(b0v, b1v, b2v, b3v, b4v, tau0, tau1, tau2, tau3, 1.0f);
        float tc = sqrtf(fmaf(xt, xt, 1.0f + xx));
        float dl = tc - xt;
        b4v += dl;
        g0 = fmaf(dl, nt0, g0); g1 = fmaf(dl, nt1, g1);
        g2 = fmaf(dl, nt2, g2); g3 = fmaf(dl, nt3, g3);
        g4 -= dl;
    }

    float r[8];
    #pragma unroll
    for (int j = 0; j < 8; ++j)
        r[j] = fmaf(b0v, hv[0][j], fmaf(b1v, hv[1][j],
               fmaf(b2v, hv[2][j], b3v * hv[3][j])));
    if (sub == 0) r[0] += b4v;

    float4* po = reinterpret_cast<float4*>(
        out + (size_t)4 * osz + (size_t)item * DD + sub * 8);
    po[0] = make_float4(r[0], r[1], r[2], r[3]);
    po[1] = make_float4(r[4], r[5], r[6], r[7]);
}

extern "C" void kernel_launch(void* const* d_in, const int* in_sizes, int n_in,
                              void* d_out, int out_size, void* d_ws, size_t ws_size,
                              hipStream_t stream)
{
    const float* x0 = (const float*)d_in[0];
    const float* x1 = (const float*)d_in[1];
    const float* x2 = (const float*)d_in[2];
    const float* x3 = (const float*)d_in[3];
    const float* W0 = (const float*)d_in[4];
    const float* b0 = (const float*)d_in[5];
    const float* W1 = (const float*)d_in[6];
    const float* b1 = (const float*)d_in[7];
    const float* W2 = (const float*)d_in[8];
    const float* b2 = (const float*)d_in[9];
    const float* W3 = (const float*)d_in[10];
    const float* b3 = (const float*)d_in[11];
    const float* es = (const float*)d_in[12];
    const float* lw = (const float*)d_in[13];

    const int n_items = in_sizes[0] / SEG;   // 262144
    const int block = 256;

    prep_kernel<<<7, block, 0, stream>>>(W0, b0, W1, b1, W2, b2, W3, b3,
                                         es, (unsigned*)d_ws);

    const int gx = (n_items + block - 1) / block;
    dim3 grid1(gx, 4, 1);
    encode_kernel<<<grid1, block, 0, stream>>>(x0, x1, x2, x3,
                                               (const unsigned*)d_ws,
                                               (float*)d_out, n_items);

    const int n_threads = n_items * 4;
    const int gx2 = (n_threads + block - 1) / block;
    fusion_kernel<<<gx2, block, 0, stream>>>(lw, (float*)d_out, n_items);
}